// Round 13
// baseline (97.107 us; speedup 1.0000x reference)
//
#include <hip/hip_runtime.h>
#include <hip/hip_bf16.h>

// ALiBi attention, B=8 L=1024 H=8 E=64, fp32 in/out, bf16 MFMA inside.
// Outputs: V [B,L,H,E] then series [B,H,L,L] concatenated in d_out.
// R13: 2-wave blocks (QBLK=32), grid 2048, CHUNK=32, 16KB LDS ->
// 8 blocks/CU (same 16 waves/CU as R12 but twice the independent
// phase-streams; barriers sync only 2 waves). Counted-vmcnt staging
// pipeline, fixed-max softmax, register-resident P (QK D-frag ==
// 16x16x16 A-frag). VT uses an 8B-slot XOR swizzle (2-way max).

typedef short short8 __attribute__((ext_vector_type(8)));
typedef short short4v __attribute__((ext_vector_type(4)));
typedef float f32x4 __attribute__((ext_vector_type(4)));
typedef unsigned short u16x4 __attribute__((ext_vector_type(4)));

#define B_ 8
#define L_ 1024
#define H_ 8
#define E_ 64
#define RSTRIDE (H_ * E_)       // 512 floats between seq rows
#define QBLK 32                 // 2 waves x 16 q-rows
#define CHUNK 32                // keys per chunk
#define NCH (L_ / CHUNK)        // 32
#define CHUNK_USH (CHUNK * E_)  // 2048 ushorts = 4KB per chunk tile

__device__ __forceinline__ unsigned short f2bf(float f) {
  return __builtin_bit_cast(unsigned short, __float2bfloat16(f));
}
__device__ __forceinline__ short8 ldfrag(const float* p) {
  float4 a = *reinterpret_cast<const float4*>(p);
  float4 b = *reinterpret_cast<const float4*>(p + 4);
  return (short8){(short)f2bf(a.x), (short)f2bf(a.y), (short)f2bf(a.z),
                  (short)f2bf(a.w), (short)f2bf(b.x), (short)f2bf(b.y),
                  (short)f2bf(b.z), (short)f2bf(b.w)};
}

__device__ __forceinline__ f32x4 mfma16(short4v a, short4v b, f32x4 c) {
#if __has_builtin(__builtin_amdgcn_mfma_f32_16x16x16bf16_1k)
  return __builtin_amdgcn_mfma_f32_16x16x16bf16_1k(a, b, c, 0, 0, 0);
#else
  asm volatile(
      "s_nop 1\n\t"
      "v_mfma_f32_16x16x16_bf16 %0, %1, %2, %0\n\t"
      "s_nop 2"
      : "+v"(c)
      : "v"(a), "v"(b));
  return c;
#endif
}

__device__ __forceinline__ void gld16(const unsigned short* g,
                                      unsigned short* l) {
  __builtin_amdgcn_global_load_lds(
      (const __attribute__((address_space(1))) unsigned int*)g,
      (__attribute__((address_space(3))) unsigned int*)l, 16, 0, 0);
}

#define BAR_VM(N)                                         \
  {                                                       \
    asm volatile("s_waitcnt vmcnt(" #N ")" ::: "memory"); \
    __builtin_amdgcn_s_barrier();                         \
    __builtin_amdgcn_sched_barrier(0);                    \
  }
#define PIN() __builtin_amdgcn_sched_barrier(0)

// ---- prep: 32-key chunks in gload-linear swizzled order ----
// K chunk (32 s x 64 e): 16B-block j' <-> (s = j'>>3, e8 = (j'&7)^(s&7)).
// VT chunk (64 e x 32 s): row e = 32 ushorts = 8 x 8B slots;
//   8B unit u = s/4 lives at slot u ^ (e&7).
__global__ __launch_bounds__(256, 4) void prep_kv(
    const float* __restrict__ Kg, const float* __restrict__ Vg,
    unsigned short* __restrict__ Kbf, unsigned short* __restrict__ VTbf) {
  __shared__ unsigned short vt[2 * CHUNK_USH];  // two VT chunks, swizzled

  const int t = threadIdx.x;
  const int id = blockIdx.x;
  const int bh = id & 63;  // id%8 = h -> same XCD as consumers
  const int sc = id >> 6;  // 64-key region 0..15 -> chunks 2sc, 2sc+1
  const int h = bh & 7, b = bh >> 3;
  const int s0 = sc * 64;

  const float* Kb = Kg + ((size_t)b * L_ + s0) * RSTRIDE + h * E_;
  const float* Vb = Vg + ((size_t)b * L_ + s0) * RSTRIDE + h * E_;
  unsigned short* Ko = Kbf + (size_t)(bh * NCH + 2 * sc) * CHUNK_USH;
  unsigned short* Vo = VTbf + (size_t)(bh * NCH + 2 * sc) * CHUNK_USH;

  // K: convert into swizzled block order (reads stay coalesced)
#pragma unroll
  for (int i = 0; i < 2; ++i) {
    const int j = t + 256 * i;  // 512 16B-blocks over 2 chunks
    const int ch = j >> 8;
    const int jj = j & 255;
    const int s = jj >> 3;
    const int e8 = (jj & 7) ^ (s & 7);
    const float* kp = Kb + (size_t)(32 * ch + s) * RSTRIDE + 8 * e8;
    float4 a = *reinterpret_cast<const float4*>(kp);
    float4 c = *reinterpret_cast<const float4*>(kp + 4);
    *reinterpret_cast<u16x4*>(&Ko[(size_t)ch * CHUNK_USH + jj * 8]) =
        (u16x4){f2bf(a.x), f2bf(a.y), f2bf(a.z), f2bf(a.w)};
    *reinterpret_cast<u16x4*>(&Ko[(size_t)ch * CHUNK_USH + jj * 8 + 4]) =
        (u16x4){f2bf(c.x), f2bf(c.y), f2bf(c.z), f2bf(c.w)};
  }
  // V: assemble swizzled VT chunks in LDS, then linear copy out
  {
    const int e = t & 63, w4 = t >> 6;
#pragma unroll
    for (int i = 0; i < 4; ++i) {
      const int s4 = 4 * w4 + 16 * i;  // 0..63
      const int ch = s4 >> 5;
      const int u = (s4 & 31) >> 2;         // 8B unit in chunk row
      const int slot = u ^ (e & 7);         // swizzled slot
      const float* vp = Vb + (size_t)s4 * RSTRIDE + e;
      u16x4 uv = {f2bf(vp[0]), f2bf(vp[RSTRIDE]), f2bf(vp[2 * RSTRIDE]),
                  f2bf(vp[3 * RSTRIDE])};
      *reinterpret_cast<u16x4*>(&vt[ch * CHUNK_USH + e * 32 + slot * 4]) = uv;
    }
  }
  __syncthreads();
#pragma unroll
  for (int i = 0; i < 2; ++i) {
    const int j = t + 256 * i;  // swizzled space is block-linear
    u16x4 u0 = *reinterpret_cast<const u16x4*>(&vt[j * 8]);
    u16x4 u1 = *reinterpret_cast<const u16x4*>(&vt[j * 8 + 4]);
    *reinterpret_cast<u16x4*>(&Vo[j * 8]) = u0;
    *reinterpret_cast<u16x4*>(&Vo[j * 8 + 4]) = u1;
  }
}

// ---- main: 2 waves x 16 q-rows, 8 blocks/CU, counted-vmcnt pipeline ----
__global__ __launch_bounds__(128, 4) void alibi_attn(
    const float* __restrict__ Qg, const unsigned short* __restrict__ Kbf,
    const unsigned short* __restrict__ VTbf, float* __restrict__ Vout,
    float* __restrict__ Pout) {
  // 16KB union: pass A = 4 K-buffers; pass B = K in [0],[1], VT in [2],[3]
  __shared__ unsigned short sBuf[4][CHUNK_USH];

  const int t = threadIdx.x;
  const int lane = t & 63;
  const int w = t >> 6;  // 0..1
  const int col = lane & 15;
  const int kg = lane >> 4;

  const int id = blockIdx.x;  // id%8 = h -> XCD-pinned scratch in L2
  const int qb = id >> 6;     // 0..31
  const int bh = id & 63;
  const int h = bh & 7;
  const int b = bh >> 3;
  const int q0 = qb * QBLK;

  const float sc_l2e = 0.125f * 1.44269504f;
  const float sl_l2e = exp2f(-(float)(h + 1) * 0.125f) * 1.44269504f;

  const unsigned short* Kc = Kbf + (size_t)bh * NCH * CHUNK_USH;
  const unsigned short* Vc = VTbf + (size_t)bh * NCH * CHUNK_USH;

  // Q B-fragments: q-row = col, k = 8*kg + j (+32 for second slice)
  short8 qf0, qf1;
  {
    const float* qp =
        Qg + ((size_t)b * L_ + q0 + 16 * w + col) * RSTRIDE + h * E_ + 8 * kg;
    qf0 = ldfrag(qp);
    qf1 = ldfrag(qp + 32);
  }

  const float kbias0 = sl_l2e * (float)(4 * kg - 1023) - 32.0f;

  // stage one 4KB chunk: 2 x gld16 per thread (segs w, 2+w)
#define STAGE(srcbase, c, dst)                                       \
  {                                                                  \
    const unsigned short* src = (srcbase) + (size_t)(c)*CHUNK_USH;   \
    _Pragma("unroll") for (int i = 0; i < 2; ++i) {                  \
      const int seg = i * 2 + w;                                     \
      gld16(src + (size_t)(seg * 64 + lane) * 8, (dst) + seg * 512); \
    }                                                                \
  }

  // ===== Pass A: z = sum exp2(u-32); 4 bufs, depth-2 prefetch =====
  float z0 = 0.f, z1 = 0.f, z2 = 0.f, z3 = 0.f;
  STAGE(Kc, 0, sBuf[0]);
  STAGE(Kc, 1, sBuf[1]);
  PIN();
  BAR_VM(2);  // chunk 0 landed; chunk 1 in flight
  for (int c = 0; c < NCH; ++c) {
    if (c + 2 < NCH) {
      STAGE(Kc, c + 2, sBuf[(c + 2) & 3]);
      PIN();
    }
    const unsigned short* kb = sBuf[c & 3];
#pragma unroll
    for (int kt = 0; kt < 2; ++kt) {
      const int row = 16 * kt + col;
      short8 k0 = *reinterpret_cast<const short8*>(
          &kb[row * 64 + ((kg ^ (row & 7)) << 3)]);
      short8 k1 = *reinterpret_cast<const short8*>(
          &kb[row * 64 + (((kg + 4) ^ (row & 7)) << 3)]);
      f32x4 acc = {0.f, 0.f, 0.f, 0.f};
      acc = __builtin_amdgcn_mfma_f32_16x16x32_bf16(k0, qf0, acc, 0, 0, 0);
      acc = __builtin_amdgcn_mfma_f32_16x16x32_bf16(k1, qf1, acc, 0, 0, 0);
      const float base = fmaf((float)(CHUNK * c + 16 * kt), sl_l2e, kbias0);
      z0 += __builtin_amdgcn_exp2f(fmaf(acc[0], sc_l2e, base));
      z1 += __builtin_amdgcn_exp2f(fmaf(acc[1], sc_l2e, base + sl_l2e));
      z2 += __builtin_amdgcn_exp2f(fmaf(acc[2], sc_l2e, base + 2.f * sl_l2e));
      z3 += __builtin_amdgcn_exp2f(fmaf(acc[3], sc_l2e, base + 3.f * sl_l2e));
    }
    if (c + 2 < NCH) {
      BAR_VM(2);
    } else {
      BAR_VM(0);
    }
  }
  float z = (z0 + z1) + (z2 + z3);
  z += __shfl_xor(z, 16, 64);
  z += __shfl_xor(z, 32, 64);
  const float minv = 1.0f / z;

  // ===== Pass B: 2K+2V buffers; per iter [4 stage][2 stores] -> vmcnt(2) ==
  f32x4 oacc[4];
#pragma unroll
  for (int et = 0; et < 4; ++et) oacc[et] = (f32x4){0.f, 0.f, 0.f, 0.f};

  float* Pb =
      Pout + ((size_t)(b * H_ + h) * L_ + q0 + 16 * w + col) * L_ + 4 * kg;

  __syncthreads();  // pass A fully done before buffer repurposing
  STAGE(Kc, 0, sBuf[0]);
  STAGE(Vc, 0, sBuf[2]);
  PIN();
  BAR_VM(0);
  for (int c = 0; c < NCH; ++c) {
    if (c + 1 < NCH) {
      STAGE(Kc, c + 1, sBuf[(c + 1) & 1]);
      STAGE(Vc, c + 1, sBuf[2 + ((c + 1) & 1)]);
      PIN();  // pin the 4 loads ahead of this iteration's 2 P-stores
    }
    const unsigned short* kb = sBuf[c & 1];
    const unsigned short* vb = sBuf[2 + (c & 1)];
#pragma unroll
    for (int kt = 0; kt < 2; ++kt) {
      const int row = 16 * kt + col;
      short8 k0 = *reinterpret_cast<const short8*>(
          &kb[row * 64 + ((kg ^ (row & 7)) << 3)]);
      short8 k1 = *reinterpret_cast<const short8*>(
          &kb[row * 64 + (((kg + 4) ^ (row & 7)) << 3)]);
      f32x4 acc = {0.f, 0.f, 0.f, 0.f};
      acc = __builtin_amdgcn_mfma_f32_16x16x32_bf16(k0, qf0, acc, 0, 0, 0);
      acc = __builtin_amdgcn_mfma_f32_16x16x32_bf16(k1, qf1, acc, 0, 0, 0);
      // V^T fragments: e = 16et+col; 8B unit u = 4kt+kg at slot u^(e&7)
      short4v vf[4];
#pragma unroll
      for (int et = 0; et < 4; ++et) {
        const int e = 16 * et + col;
        const int slot = (4 * kt + kg) ^ (e & 7);
        vf[et] =
            *reinterpret_cast<const short4v*>(&vb[e * 32 + slot * 4]);
      }
      const float base = fmaf((float)(CHUNK * c + 16 * kt), sl_l2e, kbias0);
      f32x4 pf;
      pf[0] = __builtin_amdgcn_exp2f(fmaf(acc[0], sc_l2e, base)) * minv;
      pf[1] =
          __builtin_amdgcn_exp2f(fmaf(acc[1], sc_l2e, base + sl_l2e)) * minv;
      pf[2] = __builtin_amdgcn_exp2f(fmaf(acc[2], sc_l2e, base + 2.f * sl_l2e)) *
              minv;
      pf[3] = __builtin_amdgcn_exp2f(fmaf(acc[3], sc_l2e, base + 3.f * sl_l2e)) *
              minv;
      // P store straight from D-frag (stays in flight across the barrier)
      *reinterpret_cast<f32x4*>(Pb + CHUNK * c + 16 * kt) = pf;
      // pack to bf16 A-frag (k = 4*kg + j == this lane's keys) and PV
      short4v pa = {(short)f2bf(pf[0]), (short)f2bf(pf[1]), (short)f2bf(pf[2]),
                    (short)f2bf(pf[3])};
#pragma unroll
      for (int et = 0; et < 4; ++et) oacc[et] = mfma16(pa, vf[et], oacc[et]);
    }
    // program order per iter (pinned): [4 stage loads][2 P-stores].
    // vmcnt(2) waits the loads, leaves only this iter's stores in flight.
    BAR_VM(2);
  }

  // ---- write O: q = q0+16w+4kg+r, e = 16et+col ----
  float* Vo = Vout + (((size_t)b * L_ + q0 + 16 * w) * H_ + h) * E_;
#pragma unroll
  for (int et = 0; et < 4; ++et) {
#pragma unroll
    for (int r = 0; r < 4; ++r) {
      __builtin_nontemporal_store(oacc[et][r],
                                  &Vo[(4 * kg + r) * RSTRIDE + 16 * et + col]);
    }
  }
}

extern "C" void kernel_launch(void* const* d_in, const int* in_sizes, int n_in,
                              void* d_out, int out_size, void* d_ws,
                              size_t ws_size, hipStream_t stream) {
  const float* Q = (const float*)d_in[0];
  const float* K = (const float*)d_in[1];
  const float* V = (const float*)d_in[2];
  float* out = (float*)d_out;
  float* Vo = out;                              // [B,L,H,E]
  float* Po = out + (size_t)B_ * L_ * H_ * E_;  // [B,H,L,L]
  unsigned short* Kbf = (unsigned short*)d_ws;  // 8 MB
  unsigned short* VTbf = Kbf + (size_t)B_ * H_ * L_ * E_;  // 8 MB
  hipLaunchKernelGGL(prep_kv, dim3(16 * B_ * H_), dim3(256), 0, stream, K, V,
                     Kbf, VTbf);
  hipLaunchKernelGGL(alibi_attn, dim3((L_ / QBLK) * H_ * B_), dim3(128), 0,
                     stream, Q, Kbf, VTbf, Vo, Po);
}